// Round 6
// baseline (2212.782 us; speedup 1.0000x reference)
//
#include <hip/hip_runtime.h>

// LSTMBaseline: B=2048, T=512, H=128, 4H=512, FF=64, OUT=2 ; fp32 in/out.
// R15 = R14 (4 waves x 512 regs, ALL weights AGPR-resident, zero spill,
// shfl-based cell exchange) + software-pipelined cells for single-wave
// MFMA/VALU overlap. R14 post-mortem: WRITE_SIZE=16KB proved zero spill,
// yet 1351us; MfmaUtil 26% @ 12% occupancy => in-order issue left the MFMA
// pipe idle 74%: cells depend on the SAME iteration's MFMA accs, so program
// order is [all MFMA][all VALU] with nothing to issue during the ~19.4
// cyc/MFMA pipe occupancy (96 MFMA/SIMD/step = 1862 cyc floor).
// Fix: 2 phases/step, cells shifted one iteration:
//   Phase A: cell1(it-2) [consumes accB from PREV iteration - no wait]
//            interleaved with MM0(it) (32 MFMA); barrier1 publishes h1.
//   Phase B: cell0(it) [consumes accA, complete since phase A]
//            interleaved with MM1(it-1) (64 MFMA); barrier2 publishes h0.
// accB (32 regs) carried across iterations; h1 single-buffered (write in
// phase A, read in phase B, fenced by barrier1). All cross-lane via __shfl.
// Reg budget: 384 weights + 64 acc (A+B) + ~55 work ~= 505 <= 512.
// Validation bit: WRITE_SIZE must stay ~16KB (>>1MB => in-loop spill).

#define TT 512
#define HH 128
#define FFD 64
#define BB 8
#define NT 256   // 4 waves
#define HP 136   // padded LDS row stride (ushort); 272B = 16B-aligned rows

typedef __attribute__((ext_vector_type(8))) short short8;
typedef __attribute__((ext_vector_type(4))) float f32x4;

#define L2E  1.4426950408889634f
#define L2E2 2.8853900817779268f

__device__ __forceinline__ unsigned short f2b(float f) {
    unsigned int i = __builtin_bit_cast(unsigned int, f);
    i += 0x7FFFu + ((i >> 16) & 1u);   // RNE
    return (unsigned short)(i >> 16);
}
__device__ __forceinline__ float b2f(unsigned short u) {
    return __builtin_bit_cast(float, ((unsigned int)u) << 16);
}
__device__ __forceinline__ float fexp2(float x) {
#if __has_builtin(__builtin_amdgcn_exp2f)
    return __builtin_amdgcn_exp2f(x);     // v_exp_f32
#else
    return exp2f(x);
#endif
}
__device__ __forceinline__ float frcp(float x) {
#if __has_builtin(__builtin_amdgcn_rcpf)
    return __builtin_amdgcn_rcpf(x);      // v_rcp_f32
#else
    return 1.0f / x;
#endif
}
// pre-scaled activations: y already multiplied by log2e (sigm) / 2*log2e (tanh)
__device__ __forceinline__ float sigm_s(float y) {
    return frcp(1.0f + fexp2(-y));
}
__device__ __forceinline__ float tanh_s(float y) {
    return 1.0f - 2.0f * frcp(1.0f + fexp2(y));
}
// natural-domain tanh (for cell state c)
__device__ __forceinline__ float tanh_c(float x) {
    return 1.0f - 2.0f * frcp(1.0f + fexp2(L2E2 * x));
}
// 8 consecutive fp32 -> bf16 short8 fragment, scaled
__device__ __forceinline__ short8 ldfrag(const float* p, unsigned idx, float s) {
    const float4* q = reinterpret_cast<const float4*>(p + idx);
    float4 a = q[0], b = q[1];
    short8 r;
    r[0] = (short)f2b(a.x * s); r[1] = (short)f2b(a.y * s);
    r[2] = (short)f2b(a.z * s); r[3] = (short)f2b(a.w * s);
    r[4] = (short)f2b(b.x * s); r[5] = (short)f2b(b.y * s);
    r[6] = (short)f2b(b.z * s); r[7] = (short)f2b(b.w * s);
    return r;
}

#define MFMA(a, b, c) __builtin_amdgcn_mfma_f32_16x16x32_bf16((a), (b), (c), 0, 0, 0)

// cell1: pre-activation complete in accB (bias folded); writes h1s
#define CELL1_H2(h2)                                                        \
    {                                                                       \
        const int jc_ = j0 + 16 * (h2);                                     \
        _Pragma("unroll")                                                   \
        for (int u = 0; u < 2; u++) {                                       \
            float ri = __shfl(accB[0 + (h2)][2 + u], lx, 64);               \
            float rf = __shfl(accB[2 + (h2)][2 + u], lx, 64);               \
            float rg = __shfl(accB[4 + (h2)][2 + u], lx, 64);               \
            float ro = __shfl(accB[6 + (h2)][2 + u], lx, 64);               \
            float pi = (kg < 2) ? accB[0 + (h2)][u] : ri;                   \
            float pf = (kg < 2) ? accB[2 + (h2)][u] : rf;                   \
            float pg = (kg < 2) ? accB[4 + (h2)][u] : rg;                   \
            float po = (kg < 2) ? accB[6 + (h2)][u] : ro;                   \
            float ig = sigm_s(pi), fg = sigm_s(pf);                         \
            float gg = tanh_s(pg), og = sigm_s(po);                         \
            float c = fg * c1[(h2)][u] + ig * gg;                           \
            c1[(h2)][u] = c;                                                \
            h1s[rbase + u][jc_] = f2b(og * tanh_c(c));                      \
        }                                                                   \
    }

// cell0: accA holds bias + whh0*h0; adds x-projection; writes h0b[qb]
#define CELL0_H2(h2)                                                        \
    {                                                                       \
        const int jc_ = j0 + 16 * (h2);                                     \
        f32x4 w01 = *reinterpret_cast<const f32x4*>(&wab[jc_][0]);          \
        f32x4 w23 = *reinterpret_cast<const f32x4*>(&wab[jc_][4]);          \
        _Pragma("unroll")                                                   \
        for (int u = 0; u < 2; u++) {                                       \
            float ri = __shfl(accA[0 + (h2)][2 + u], lx, 64);               \
            float rf = __shfl(accA[2 + (h2)][2 + u], lx, 64);               \
            float rg = __shfl(accA[4 + (h2)][2 + u], lx, 64);               \
            float ro = __shfl(accA[6 + (h2)][2 + u], lx, 64);               \
            float vi = (kg < 2) ? accA[0 + (h2)][u] : ri;                   \
            float vf = (kg < 2) ? accA[2 + (h2)][u] : rf;                   \
            float vg = (kg < 2) ? accA[4 + (h2)][u] : rg;                   \
            float vo = (kg < 2) ? accA[6 + (h2)][u] : ro;                   \
            float pi = vi + xh[u] * w01[0] + xg[u] * w01[1];                \
            float pf = vf + xh[u] * w01[2] + xg[u] * w01[3];                \
            float pg = vg + xh[u] * w23[0] + xg[u] * w23[1];                \
            float po = vo + xh[u] * w23[2] + xg[u] * w23[3];                \
            float ig = sigm_s(pi), fg = sigm_s(pf);                         \
            float gg = tanh_s(pg), og = sigm_s(po);                         \
            float c = fg * c0[(h2)][u] + ig * gg;                           \
            c0[(h2)][u] = c;                                                \
            h0b[qb][rbase + u][jc_] = f2b(og * tanh_c(c));                  \
        }                                                                   \
    }

__global__ __launch_bounds__(NT, 1) void lstm2_fused(
    const float* __restrict__ hr,
    const float* __restrict__ glu,
    const float* __restrict__ wih0,
    const float* __restrict__ whh0,
    const float* __restrict__ bih0,
    const float* __restrict__ bhh0,
    const float* __restrict__ wih1,
    const float* __restrict__ whh1,
    const float* __restrict__ bih1,
    const float* __restrict__ bhh1,
    const float* __restrict__ w1,
    const float* __restrict__ b1,
    const float* __restrict__ w2,
    const float* __restrict__ b2,
    float* __restrict__ out)
{
    // h0(t) in buffer t&1; h1 single-buffered (phaseA write -> phaseB read).
    __shared__ __align__(16) unsigned short h0b[2][16][HP];
    __shared__ __align__(16) unsigned short h1s[16][HP];
    __shared__ __align__(16) float b0t[HH][4];          // scaled bias0 [col][g]
    __shared__ __align__(16) float b1t[HH][4];          // scaled bias1 [col][g]
    __shared__ __align__(16) float wab[HH][8];          // scaled wih0 [col][{wa,wb}x4g]
    __shared__ float hid[BB][FFD];

    const int tid  = threadIdx.x;
    const int lane = tid & 63;
    const int wv   = tid >> 6;        // 0..3
    const int nrow = lane & 15;       // MFMA m (A) / n (B) index
    const int kg   = lane >> 4;       // MFMA k-group 0..3
    const int lx   = lane ^ 32;       // cross-half partner for __shfl
    const int b0   = blockIdx.x * BB;

    // ---- init LDS ----
    {
        unsigned short* p0 = &h0b[0][0][0];
        unsigned short* p1 = &h1s[0][0];
        for (int i = tid; i < 2 * 16 * HP; i += NT) p0[i] = 0;
        for (int i = tid; i < 16 * HP; i += NT) p1[i] = 0;
        for (int i = tid; i < 4 * HH; i += NT) {      // i = 128g + col
            int g  = i >> 7;
            int jc = i & (HH - 1);
            float s = (g == 2) ? L2E2 : L2E;
            b0t[jc][g] = (bih0[i] + bhh0[i]) * s;
            b1t[jc][g] = (bih1[i] + bhh1[i]) * s;
            wab[jc][2 * g]     = wih0[2 * i] * s;
            wab[jc][2 * g + 1] = wih0[2 * i + 1] * s;
        }
    }

    // ---- resident weight frags: 96 frags = 384 regs. t = g*2+h2 ----
    // B-frag 16x16x32: lane(n=lane&15, q=lane>>4) holds B[k=32kt+8q+e][n]=W[col][k]
    short8 W0[8][4], Wi[8][4], Wh[8][4];
#pragma unroll
    for (int g = 0; g < 4; g++)
#pragma unroll
        for (int h2 = 0; h2 < 2; h2++) {
            const float s = (g == 2) ? L2E2 : L2E;
            const int t = g * 2 + h2;
            unsigned gc = (unsigned)(128 * g + 32 * wv + 16 * h2 + nrow);
#pragma unroll
            for (int kt = 0; kt < 4; kt++) {
                unsigned off = gc * HH + kt * 32 + kg * 8;
                W0[t][kt] = ldfrag(whh0, off, s);
                asm volatile("" : "+a"(W0[t][kt]));
            }
#pragma unroll
            for (int kt = 0; kt < 4; kt++) {
                unsigned off = gc * HH + kt * 32 + kg * 8;
                Wi[t][kt] = ldfrag(wih1, off, s);
                asm volatile("" : "+a"(Wi[t][kt]));
            }
#pragma unroll
            for (int kt = 0; kt < 4; kt++) {
                unsigned off = gc * HH + kt * 32 + kg * 8;
                Wh[t][kt] = ldfrag(whh1, off, s);
                asm volatile("" : "+a"(Wh[t][kt]));
            }
        }

    const int j0    = 32 * wv + nrow;       // first owned col; second = j0+16
    const int rbase = (kg & 1) * 4 + (kg & 2);   // rows {rbase, rbase+1}
    float c0[2][2] = {{0.f, 0.f}, {0.f, 0.f}};   // [h2][u]
    float c1[2][2] = {{0.f, 0.f}, {0.f, 0.f}};
    f32x4 accB[8];                                // carried across iterations
#pragma unroll
    for (int t = 0; t < 8; t++) { f32x4 z = {0.f, 0.f, 0.f, 0.f}; accB[t] = z; }
    __syncthreads();

    // ---- recurrence: 2 phases / 2 barriers per iteration ----
    // Iteration it: phaseA = cell1(it-2) || MM0(it); phaseB = cell0(it) || MM1(it-1).
    for (int it = 0; it < TT + 2; it++) {
        const int p  = (it + 1) & 1;   // buffer holding h0(it-1)
        const int qb = it & 1;         // buffer for h0(it)
        const bool doA  = (it < TT);             // MM0(it), cell0(it)
        const bool doB  = (it >= 1) && (it <= TT);   // MM1(it-1)
        const bool doC1 = (it >= 2);             // cell1(it-2) from carried accB

        // x for cell0 (rows rbase, rbase+1) — issued early, L1-resident
        float xh[2], xg[2];
        if (doA) {
#pragma unroll
            for (int u = 0; u < 2; u++) {
                unsigned gi = (unsigned)(b0 + rbase + u) * TT + it;
                xh[u] = hr[gi];
                xg[u] = glu[gi];
            }
        }

        f32x4 accA[8];
        // ---------- phase A: cell1(it-2) interleaved with MM0(it) ----------
        if (doC1) CELL1_H2(0)
        if (doA) {
            short8 a0[4];
#pragma unroll
            for (int kt = 0; kt < 4; kt++)
                a0[kt] = *reinterpret_cast<const short8*>(&h0b[p][nrow][kt * 32 + kg * 8]);
            {
                f32x4 bv0 = *reinterpret_cast<const f32x4*>(&b0t[j0][0]);
                f32x4 bv1 = *reinterpret_cast<const f32x4*>(&b0t[j0 + 16][0]);
#pragma unroll
                for (int g = 0; g < 4; g++) {
                    float ba = bv0[g], bb = bv1[g];
                    f32x4 za = {ba, ba, ba, ba}; accA[2 * g]     = za;
                    f32x4 zb = {bb, bb, bb, bb}; accA[2 * g + 1] = zb;
                }
            }
#pragma unroll
            for (int kt = 0; kt < 4; kt++)
#pragma unroll
                for (int t = 0; t < 8; t++)
                    accA[t] = MFMA(a0[kt], W0[t][kt], accA[t]);
        }
        if (doC1) CELL1_H2(1)
        __syncthreads();   // barrier1: h1(it-2) visible for MM1 below

        // ---------- phase B: cell0(it) interleaved with MM1(it-1) ----------
        if (doB) {
            {
                f32x4 bv0 = *reinterpret_cast<const f32x4*>(&b1t[j0][0]);
                f32x4 bv1 = *reinterpret_cast<const f32x4*>(&b1t[j0 + 16][0]);
#pragma unroll
                for (int g = 0; g < 4; g++) {
                    float ba = bv0[g], bb = bv1[g];
                    f32x4 za = {ba, ba, ba, ba}; accB[2 * g]     = za;
                    f32x4 zb = {bb, bb, bb, bb}; accB[2 * g + 1] = zb;
                }
            }
            // part1: h0(it-1) @ wih1^T
#pragma unroll
            for (int kt = 0; kt < 4; kt++) {
                short8 a0 = *reinterpret_cast<const short8*>(&h0b[p][nrow][kt * 32 + kg * 8]);
#pragma unroll
                for (int t = 0; t < 8; t++)
                    accB[t] = MFMA(a0, Wi[t][kt], accB[t]);
            }
        }
        if (doA) CELL0_H2(0)
        if (doB) {
            // part2: h1(it-2) @ whh1^T
#pragma unroll
            for (int kt = 0; kt < 4; kt++) {
                short8 a1 = *reinterpret_cast<const short8*>(&h1s[nrow][kt * 32 + kg * 8]);
#pragma unroll
                for (int t = 0; t < 8; t++)
                    accB[t] = MFMA(a1, Wh[t][kt], accB[t]);
            }
        }
        if (doA) CELL0_H2(1)
        __syncthreads();   // barrier2: h0(it) visible for MM0/MM1p1 next iter
    }

    // ---- head: h1 final = h1(TT-1), written at it=TT+1 phase A ----
    for (int idx = tid; idx < BB * FFD; idx += NT) {
        int r  = idx >> 6;
        int ff = idx & 63;
        float a2 = 0.f;
        for (int k = 0; k < HH; k++)
            a2 += b2f(h1s[r][k]) * w1[(unsigned)ff * HH + k];
        hid[r][ff] = fmaxf(a2 + b1[ff], 0.f);
    }
    __syncthreads();
    if (tid < 16) {
        int r = tid >> 1;
        int o = tid & 1;
        float a2 = b2[o];
        for (int k = 0; k < FFD; k++)
            a2 += hid[r][k] * w2[(unsigned)o * FFD + k];
        out[(b0 + r) * 2 + o] = a2;    // fp32 output
    }
}

extern "C" void kernel_launch(void* const* d_in, const int* in_sizes, int n_in,
                              void* d_out, int out_size, void* d_ws, size_t ws_size,
                              hipStream_t stream) {
    const float* hr   = (const float*)d_in[0];
    const float* glu  = (const float*)d_in[1];
    const float* wih0 = (const float*)d_in[2];
    const float* whh0 = (const float*)d_in[3];
    const float* bih0 = (const float*)d_in[4];
    const float* bhh0 = (const float*)d_in[5];
    const float* wih1 = (const float*)d_in[6];
    const float* whh1 = (const float*)d_in[7];
    const float* bih1 = (const float*)d_in[8];
    const float* bhh1 = (const float*)d_in[9];
    const float* w1   = (const float*)d_in[10];
    const float* b1   = (const float*)d_in[11];
    const float* w2   = (const float*)d_in[12];
    const float* b2   = (const float*)d_in[13];
    float* out = (float*)d_out;

    lstm2_fused<<<dim3(2048 / BB), dim3(NT), 0, stream>>>(
        hr, glu, wih0, whh0, bih0, bhh0, wih1, whh1, bih1, bhh1,
        w1, b1, w2, b2, out);
}